// Round 13
// baseline (153.492 us; speedup 1.0000x reference)
//
#include <hip/hip_runtime.h>

// RepulsionLoss: points [B=4, N=8192, 3] fp32 -> scalar.
// Round 13: R12's fixed-trip sentinel-slab query, MEMORY-SAFE.
// R12 bug: slab was 512 slots but 9 neighbor rows average ~513 staged points
// -> LDS overflow on ~half the blocks. Fix: slab = 9*CAP = 1152 slots
// (18.4 KB, R10's proven footprint); hot loop = compile-time 80 trips over
// the first 640 slots (mean 512 + 5.7 sigma; sentinel-padded), plus a
// runtime tail loop [640, nst) that is ~never taken but keeps exactness.
// 3 dispatches: memset(2.3KB) + scatter + query(576 x 512).

#define B_     4
#define N_     8192
#define KNN_   8
#define G_     12
#define NR_    (G_ * G_)        // 144 rows per batch
#define CAP_   128              // row capacity; Poisson(57) overflow ~1e-15
#define SLAB_  (9 * CAP_)       // 1152 slots worst case (18432 B)
#define FIXED_ 640              // compile-time scan window: 80 trips x 8 lanes

constexpr float GF_     = (float)G_;
constexpr float CELL_   = 1.0f / GF_;
constexpr float RADIUS_ = 0.07f;
constexpr float INV_H2_ = 1.0f / (0.03f * 0.03f);
constexpr float SCALE_  = 0.1f / (float)(B_ * N_ * KNN_);   // ALPHA / (B*N*K)
constexpr float SENT_   = 1e15f;   // sentinel coord; d2 ~ 3e30 > 1e30 init

__device__ __forceinline__ int cell_coord(float x) {
    int c = (int)(x * GF_);
    return min(max(c, 0), G_ - 1);
}

__device__ __forceinline__ void insert8(float (&t)[KNN_], float v) {
#pragma unroll
    for (int k = 0; k < KNN_; k++) {
        const float lo = fminf(t[k], v);
        v = fmaxf(t[k], v);
        t[k] = lo;
    }
}

// 3-stage bitonic merge across the 8 lanes of a point-group (md=1,2,4):
// all 8 lanes end with the sorted min-8 of the union. Disjoint lists only.
__device__ __forceinline__ void merge8(float (&t)[KNN_]) {
#pragma unroll
    for (int md = 1; md <= 4; md <<= 1) {
        float u[KNN_];
#pragma unroll
        for (int i2 = 0; i2 < KNN_; i2++)
            u[i2] = fminf(t[i2], __shfl_xor(t[KNN_ - 1 - i2], md));
#pragma unroll
        for (int d = 4; d >= 1; d >>= 1) {
#pragma unroll
            for (int i2 = 0; i2 < KNN_; i2++) {
                if ((i2 & d) == 0) {
                    const float a = u[i2], e = u[i2 + d];
                    u[i2] = fminf(a, e); u[i2 + d] = fmaxf(a, e);
                }
            }
        }
#pragma unroll
        for (int i2 = 0; i2 < KNN_; i2++) t[i2] = u[i2];
    }
}

__global__ __launch_bounds__(256) void scatter_kernel(const float* __restrict__ pts,
                                                      int* __restrict__ cnt,
                                                      float4* __restrict__ bucket,
                                                      float* __restrict__ out) {
    const int g = blockIdx.x * 256 + threadIdx.x;   // 0..B*N-1
    if (g == 0) out[0] = 0.0f;                      // out re-poisoned each replay
    const int b = g >> 13;
    const float x = pts[g * 3 + 0], y = pts[g * 3 + 1], z = pts[g * 3 + 2];
    const int row = b * NR_ + cell_coord(z) * G_ + cell_coord(y);
    const int slot = atomicAdd(&cnt[row], 1);
    if (slot < CAP_)
        bucket[(size_t)row * CAP_ + slot] = make_float4(x, y, z, 0.0f);
}

// 576 blocks x 512 threads: block = (batch, row). 64 point-groups x 8 splits.
__global__ __launch_bounds__(512, 2) void query_kernel(const int* __restrict__ cnt,
                                                       const float4* __restrict__ bucket,
                                                       float* __restrict__ out) {
    __shared__ float4 spts[SLAB_];      // 18432 B (worst case, never overflows)
    __shared__ int    roff[10], rN[9];

    const int tid   = threadIdx.x;
    const int b     = blockIdx.x / NR_;
    const int rowid = blockIdx.x % NR_;
    const int cz    = rowid / G_, cy = rowid % G_;

    // ---- neighbor-row counts
    if (tid < 9) {
        const int z = cz + tid / 3 - 1, y = cy + tid % 3 - 1;
        rN[tid] = ((unsigned)z < G_ && (unsigned)y < G_)
                    ? min(cnt[b * NR_ + z * G_ + y], CAP_) : 0;
    }
    // sentinel-fill the fixed scan window [0, FIXED_)
    if (tid < FIXED_ - 512) spts[512 + tid] = make_float4(SENT_, SENT_, SENT_, 0.0f);
    spts[tid] = make_float4(SENT_, SENT_, SENT_, 0.0f);
    __syncthreads();
    if (tid == 0) {
        int run = 0;
        for (int r = 0; r < 9; r++) { roff[r] = run; run += rN[r]; }
        roff[9] = run;
    }
    __syncthreads();

    // ---- coalesced staging: 9 x 128 virtual slots over 512 threads (3 passes)
#pragma unroll
    for (int v = 0; v < 3; v++) {
        const int vs = v * 512 + tid;            // 0..1535 covers 1152
        const int r  = vs >> 7, j = vs & 127;
        if (r < 9 && j < rN[r]) {
            const int z = cz + r / 3 - 1, y = cy + r % 3 - 1;
            spts[roff[r] + j] = bucket[(size_t)(b * NR_ + z * G_ + y) * CAP_ + j];
        }
    }
    __syncthreads();

    const int hbase = roff[4], nrow = rN[4], nst = roff[9];
    const int s   = tid & 7;                     // 8-way split
    const int grp = tid >> 3;                    // 0..63 point-group
    float lane_sum = 0.0f;

    for (int q = grp; q < nrow; q += 64) {
        const float4 P = spts[hbase + q];
        const float px = P.x, py = P.y, pz = P.z;

        float t[KNN_];
#pragma unroll
        for (int k = 0; k < KNN_; k++) t[k] = 1e30f;

        // THE loop: compile-time 80 trips, LDS-fed, uniform for every lane.
        // Lanes of a group read 8 consecutive float4 (conflict-free); the 8
        // groups of a wave read identical addresses (broadcast).
#pragma unroll 4
        for (int jj = 0; jj < FIXED_ / 8; jj++) {
            const float4 Q = spts[jj * 8 + s];
            const float dx = px - Q.x, dy = py - Q.y, dz = pz - Q.z;
            const float d2 = dx * dx + dy * dy + dz * dz;
            if (d2 < t[KNN_ - 1]) insert8(t, d2);
        }
        // exactness tail: only if the staged slab exceeds the fixed window
        // (P ~ 5.7 sigma; ~never executes but keeps the result exact).
        for (int j = FIXED_ + s; j < nst; j += 8) {
            const float4 Q = spts[j];
            const float dx = px - Q.x, dy = py - Q.y, dz = pz - Q.z;
            const float d2 = dx * dx + dy * dy + dz * dz;
            if (d2 < t[KNN_ - 1]) insert8(t, d2);
        }

        // True merged 8th bound via temp copy (t stays disjoint slices).
        float m;
        {
            float tmp[KNN_];
#pragma unroll
            for (int k = 0; k < KNN_; k++) tmp[k] = t[k];
            merge8(tmp);
            m = tmp[KNN_ - 1];
        }

        // Exact 2D-ring fallback: unseen => |dy| or |dz| >= 2 cells =>
        // d >= (r-1)*cell for ring r. Scan while ((r-1)*cell)^2 < m.
        if (m > CELL_ * CELL_) {
            for (int r = 2; r < G_; r++) {
                const float dmin = (float)(r - 1) * CELL_;
                if (dmin * dmin >= m) break;
                for (int dz2 = -r; dz2 <= r; ++dz2) {
                    const int z = cz + dz2; if ((unsigned)z >= G_) continue;
                    for (int dy2 = -r; dy2 <= r; ++dy2) {
                        if (max(abs(dz2), abs(dy2)) != r) continue;
                        const int y = cy + dy2; if ((unsigned)y >= G_) continue;
                        const int gi = b * NR_ + z * G_ + y;
                        const int n2 = min(cnt[gi], CAP_);
                        const float4* cp = bucket + (size_t)gi * CAP_;
                        for (int j = s; j < n2; j += 8) {
                            const float4 Q = cp[j];
                            const float ddx = px - Q.x, ddy = py - Q.y, ddz = pz - Q.z;
                            const float d2 = ddx * ddx + ddy * ddy + ddz * ddz;
                            if (d2 < t[KNN_ - 1]) insert8(t, d2);
                        }
                    }
                }
                float mm = t[KNN_ - 1];
                mm = fminf(mm, __shfl_xor(mm, 1));
                mm = fminf(mm, __shfl_xor(mm, 2));
                mm = fminf(mm, __shfl_xor(mm, 4));
                m = fminf(m, mm);
            }
        }

        merge8(t);   // final exact top-8 (disjoint slices)

        if (s == 0) {
#pragma unroll
            for (int k = 0; k < KNN_; k++) {
                const float dm = fmaxf(t[k], 1e-12f);   // self: d2=0 -> dn=1e-6
                const float dn = sqrtf(dm);
                lane_sum += (RADIUS_ - dn) * __expf(-dm * INV_H2_);
            }
        }
    }

    // per-wave reduction, one atomic per wave (8 waves/block)
#pragma unroll
    for (int off = 1; off < 64; off <<= 1) lane_sum += __shfl_xor(lane_sum, off);
    if ((tid & 63) == 0) atomicAdd(out, lane_sum * SCALE_);
}

extern "C" void kernel_launch(void* const* d_in, const int* in_sizes, int n_in,
                              void* d_out, int out_size, void* d_ws, size_t ws_size,
                              hipStream_t stream) {
    const float* pts = (const float*)d_in[0];
    float*       out = (float*)d_out;

    char* ws = (char*)d_ws;
    float4* bucket = (float4*)(ws);                               // B*NR*CAP*16 = 1179648 B
    int*    counts = (int*)(ws + (size_t)B_ * NR_ * CAP_ * 16);   // B*NR*4      =    2304 B

    hipMemsetAsync(counts, 0, B_ * NR_ * sizeof(int), stream);
    scatter_kernel<<<B_ * N_ / 256, 256, 0, stream>>>(pts, counts, bucket, out);
    query_kernel  <<<B_ * NR_,      512, 0, stream>>>(counts, bucket, out);
}

// Round 14
// 150.068 us; speedup vs baseline: 1.0228x; 1.0228x over previous
//
#include <hip/hip_runtime.h>

// RepulsionLoss: points [B=4, N=8192, 3] fp32 -> scalar.
// Round 14: BRANCHLESS always-insert fixed-trip slab query.
// R13 evidence: with ~80 cands/lane the per-lane insert rate is ~33%, so the
// divergent insert fires every trip and its serial min/max chain kills
// pipelining (VALU 18%). Fix: run insert8 UNCONDITIONALLY (inserting a
// non-qualifying value is a no-op) -> zero branches, zero divergence,
// uniform issue-bound loop (~50 cy/wave-trip). 21M evals ~= 7us ideal.
// Slab = 9 neighbor rows, 1152 worst-case slots, sentinel-padded fixed
// window of 640 (mean 513 + 5.5 sigma); runtime tail + exact 2D-ring
// fallback (~6% edge points) keep it exact.
// 3 dispatches: memset(2.3KB) + scatter + query(576 x 512).

#define B_     4
#define N_     8192
#define KNN_   8
#define G_     12
#define NR_    (G_ * G_)        // 144 rows per batch
#define CAP_   128              // row capacity; Poisson(57) overflow ~1e-15
#define SLAB_  (9 * CAP_)       // 1152 worst-case slots (18432 B)
#define FIXED_ 640              // compile-time window: 80 trips x 8 lanes

constexpr float GF_     = (float)G_;
constexpr float CELL_   = 1.0f / GF_;
constexpr float RADIUS_ = 0.07f;
constexpr float INV_H2_ = 1.0f / (0.03f * 0.03f);
constexpr float SCALE_  = 0.1f / (float)(B_ * N_ * KNN_);   // ALPHA / (B*N*K)
constexpr float SENT_   = 1e15f;   // sentinel coord; d2 ~ 3e30 > 1e30 init

__device__ __forceinline__ int cell_coord(float x) {
    int c = (int)(x * GF_);
    return min(max(c, 0), G_ - 1);
}

// Branchless sorted-8 insert: if v >= t[7] this is a no-op (v falls out).
__device__ __forceinline__ void insert8(float (&t)[KNN_], float v) {
#pragma unroll
    for (int k = 0; k < KNN_; k++) {
        const float lo = fminf(t[k], v);
        v = fmaxf(t[k], v);
        t[k] = lo;
    }
}

// 3-stage bitonic merge across the 8 lanes of a point-group (md=1,2,4):
// all 8 lanes end with the sorted min-8 of the union. Disjoint lists only.
__device__ __forceinline__ void merge8(float (&t)[KNN_]) {
#pragma unroll
    for (int md = 1; md <= 4; md <<= 1) {
        float u[KNN_];
#pragma unroll
        for (int i2 = 0; i2 < KNN_; i2++)
            u[i2] = fminf(t[i2], __shfl_xor(t[KNN_ - 1 - i2], md));
#pragma unroll
        for (int d = 4; d >= 1; d >>= 1) {
#pragma unroll
            for (int i2 = 0; i2 < KNN_; i2++) {
                if ((i2 & d) == 0) {
                    const float a = u[i2], e = u[i2 + d];
                    u[i2] = fminf(a, e); u[i2 + d] = fmaxf(a, e);
                }
            }
        }
#pragma unroll
        for (int i2 = 0; i2 < KNN_; i2++) t[i2] = u[i2];
    }
}

__global__ __launch_bounds__(256) void scatter_kernel(const float* __restrict__ pts,
                                                      int* __restrict__ cnt,
                                                      float4* __restrict__ bucket,
                                                      float* __restrict__ out) {
    const int g = blockIdx.x * 256 + threadIdx.x;   // 0..B*N-1
    if (g == 0) out[0] = 0.0f;                      // out re-poisoned each replay
    const int b = g >> 13;
    const float x = pts[g * 3 + 0], y = pts[g * 3 + 1], z = pts[g * 3 + 2];
    const int row = b * NR_ + cell_coord(z) * G_ + cell_coord(y);
    const int slot = atomicAdd(&cnt[row], 1);
    if (slot < CAP_)
        bucket[(size_t)row * CAP_ + slot] = make_float4(x, y, z, 0.0f);
}

// 576 blocks x 512 threads: block = (batch, row). 64 point-groups x 8 splits.
__global__ __launch_bounds__(512, 2) void query_kernel(const int* __restrict__ cnt,
                                                       const float4* __restrict__ bucket,
                                                       float* __restrict__ out) {
    __shared__ float4 spts[SLAB_];      // 18432 B worst case
    __shared__ int    roff[10], rN[9];

    const int tid   = threadIdx.x;
    const int b     = blockIdx.x / NR_;
    const int rowid = blockIdx.x % NR_;
    const int cz    = rowid / G_, cy = rowid % G_;

    if (tid < 9) {
        const int z = cz + tid / 3 - 1, y = cy + tid % 3 - 1;
        rN[tid] = ((unsigned)z < G_ && (unsigned)y < G_)
                    ? min(cnt[b * NR_ + z * G_ + y], CAP_) : 0;
    }
    // sentinel-fill the fixed scan window [0, FIXED_)
    spts[tid] = make_float4(SENT_, SENT_, SENT_, 0.0f);
    if (tid < FIXED_ - 512) spts[512 + tid] = make_float4(SENT_, SENT_, SENT_, 0.0f);
    __syncthreads();
    if (tid == 0) {
        int run = 0;
        for (int r = 0; r < 9; r++) { roff[r] = run; run += rN[r]; }
        roff[9] = run;
    }
    __syncthreads();

    // coalesced staging: 9 x 128 virtual slots over 512 threads (3 passes)
#pragma unroll
    for (int v = 0; v < 3; v++) {
        const int vs = v * 512 + tid;            // 0..1535 covers 1152
        const int r  = vs >> 7, j = vs & 127;
        if (r < 9 && j < rN[r]) {
            const int z = cz + r / 3 - 1, y = cy + r % 3 - 1;
            spts[roff[r] + j] = bucket[(size_t)(b * NR_ + z * G_ + y) * CAP_ + j];
        }
    }
    __syncthreads();

    const int hbase = roff[4], nrow = rN[4], nst = roff[9];
    const int s   = tid & 7;                     // 8-way split
    const int grp = tid >> 3;                    // 0..63 point-group
    float lane_sum = 0.0f;

    for (int q = grp; q < nrow; q += 64) {
        const float4 P = spts[hbase + q];
        const float px = P.x, py = P.y, pz = P.z;

        float t[KNN_];
#pragma unroll
        for (int k = 0; k < KNN_; k++) t[k] = 1e30f;

        // THE loop: compile-time 80 trips, LDS-fed, BRANCHLESS. Every trip:
        // 1 ds_read_b128 + ~6 dist VALU + 16 min/max. No divergence, no
        // branch, fully unrollable. Sentinels (d2~3e30) never displace.
#pragma unroll 4
        for (int jj = 0; jj < FIXED_ / 8; jj++) {
            const float4 Q = spts[jj * 8 + s];
            const float dx = px - Q.x, dy = py - Q.y, dz = pz - Q.z;
            const float d2 = fmaf(dx, dx, fmaf(dy, dy, dz * dz));
            insert8(t, d2);
        }
        // exactness tail (slab beyond the fixed window; ~never executes)
        for (int j = FIXED_ + s; j < nst; j += 8) {
            const float4 Q = spts[j];
            const float dx = px - Q.x, dy = py - Q.y, dz = pz - Q.z;
            insert8(t, fmaf(dx, dx, fmaf(dy, dy, dz * dz)));
        }

        merge8(t);                 // all 8 lanes: sorted union top-8
        float m = t[KNN_ - 1];     // true merged 8th bound

        // Exact 2D-ring fallback: unseen => |dy| or |dz| >= 2 cells =>
        // d >= (r-1)*cell for ring r. ~6% of points (edges), block-clustered.
        if (m > CELL_ * CELL_) {
            for (int r = 2; r < G_; r++) {
                const float dmin = (float)(r - 1) * CELL_;
                if (dmin * dmin >= m) break;
                float f[KNN_];
#pragma unroll
                for (int k = 0; k < KNN_; k++) f[k] = 1e30f;
                for (int dz2 = -r; dz2 <= r; ++dz2) {
                    const int z = cz + dz2; if ((unsigned)z >= G_) continue;
                    for (int dy2 = -r; dy2 <= r; ++dy2) {
                        if (max(abs(dz2), abs(dy2)) != r) continue;
                        const int y = cy + dy2; if ((unsigned)y >= G_) continue;
                        const int gi = b * NR_ + z * G_ + y;
                        const int n2 = min(cnt[gi], CAP_);
                        const float4* cp = bucket + (size_t)gi * CAP_;
                        for (int j = s; j < n2; j += 8) {
                            const float4 Q = cp[j];
                            const float ddx = px - Q.x, ddy = py - Q.y, ddz = pz - Q.z;
                            insert8(f, fmaf(ddx, ddx, fmaf(ddy, ddy, ddz * ddz)));
                        }
                    }
                }
                merge8(f);                       // disjoint slices -> valid
#pragma unroll
                for (int k = 0; k < KNN_; k++) insert8(t, f[k]);  // fold
                m = t[KNN_ - 1];
            }
        }

        if (s == 0) {
#pragma unroll
            for (int k = 0; k < KNN_; k++) {
                const float dm = fmaxf(t[k], 1e-12f);   // self: d2=0 -> dn=1e-6
                const float dn = sqrtf(dm);
                lane_sum += (RADIUS_ - dn) * __expf(-dm * INV_H2_);
            }
        }
    }

    // per-wave reduction, one atomic per wave (8 waves/block)
#pragma unroll
    for (int off = 1; off < 64; off <<= 1) lane_sum += __shfl_xor(lane_sum, off);
    if ((tid & 63) == 0) atomicAdd(out, lane_sum * SCALE_);
}

extern "C" void kernel_launch(void* const* d_in, const int* in_sizes, int n_in,
                              void* d_out, int out_size, void* d_ws, size_t ws_size,
                              hipStream_t stream) {
    const float* pts = (const float*)d_in[0];
    float*       out = (float*)d_out;

    char* ws = (char*)d_ws;
    float4* bucket = (float4*)(ws);                               // B*NR*CAP*16 = 1179648 B
    int*    counts = (int*)(ws + (size_t)B_ * NR_ * CAP_ * 16);   // B*NR*4      =    2304 B

    hipMemsetAsync(counts, 0, B_ * NR_ * sizeof(int), stream);
    scatter_kernel<<<B_ * N_ / 256, 256, 0, stream>>>(pts, counts, bucket, out);
    query_kernel  <<<B_ * NR_,      512, 0, stream>>>(counts, bucket, out);
}